// Round 1
// baseline (104.980 us; speedup 1.0000x reference)
//
#include <hip/hip_runtime.h>
#include <math.h>

// ---- workspace layout (float offsets) ----
#define NSLOT    32
#define WS_E     0                       // 512 floats: e vector (last row)
#define WS_HPRE  512                     // 32*512 floats: partial accumulators
#define WS_H     (512 + NSLOT*512)       // 512: h = sigmoid(hpre)
#define WS_T1    (WS_H + 512)            // 512: h@Wmu.T + bmu
#define WS_SP    (WS_T1 + 512)           // 512: h@Wsig.T + bsig  (= log sig)
#define WS_MU    (WS_SP + 512)           // 512: mu
#define WS_AL    (WS_MU + 512)           // 8:  h@Wal.T + bal

// ---------------------------------------------------------------------------
// Kernel 1: e = relu(W2 @ relu(W1 @ cur + b1) + b2) for cur = X[4094]; also
// zero the NSLOT partial-accumulator slots (must re-zero every launch).
// ---------------------------------------------------------------------------
__global__ __launch_bounds__(512) void k_e(const float* __restrict__ X,
    const float* __restrict__ W1, const float* __restrict__ b1,
    const float* __restrict__ W2, const float* __restrict__ b2,
    float* __restrict__ ws)
{
    __shared__ float cur[64];
    __shared__ float e1[512];
    int t = threadIdx.x;
    if (t < 64) cur[t] = X[4094 * 64 + t];
    __syncthreads();
    {
        const float4* w = (const float4*)(W1 + (size_t)t * 64);
        float s = 0.f;
#pragma unroll
        for (int k = 0; k < 16; ++k) {
            float4 wv = w[k];
            s += wv.x * cur[4*k] + wv.y * cur[4*k+1] + wv.z * cur[4*k+2] + wv.w * cur[4*k+3];
        }
        e1[t] = fmaxf(s + b1[t], 0.f);
    }
    __syncthreads();
    {
        const float4* w = (const float4*)(W2 + (size_t)t * 512);
        float s = 0.f;
#pragma unroll 8
        for (int k = 0; k < 128; ++k) {
            float4 wv = w[k];
            s += wv.x * e1[4*k] + wv.y * e1[4*k+1] + wv.z * e1[4*k+2] + wv.w * e1[4*k+3];
        }
        ws[WS_E + t] = fmaxf(s + b2[t], 0.f);
    }
#pragma unroll
    for (int s2 = 0; s2 < NSLOT; ++s2)
        ws[WS_HPRE + s2 * 512 + t] = 0.f;
}

// ---------------------------------------------------------------------------
// Kernel 2: h_pre[j] += sum_{i,d} prev[i]*e[d]*A[i,d,j].
// Grid 2048: block b -> i = b>>2, d-chunk = (b&3)*128. Rows with e[d]==0 are
// skipped exactly (bit-identical: they contribute 0). Deterministic ballot
// compaction of the nonzero d's, then float4 streaming 4 rows deep.
// ---------------------------------------------------------------------------
__global__ __launch_bounds__(256) void k_contract(const float* __restrict__ A,
    const float* __restrict__ prev, float* __restrict__ ws)
{
    __shared__ float cvals[128];
    __shared__ unsigned short idxs[128];
    __shared__ int cnts[2];
    __shared__ float4 comb[128];

    int t = threadIdx.x;
    int b = blockIdx.x;
    int i = b >> 2;
    int d0 = (b & 3) << 7;
    const float* e = ws + WS_E;

    float c = 0.f; bool nz = false;
    if (t < 128) {
        c = prev[i] * e[d0 + t];
        nz = (c != 0.f);
    }
    unsigned long long bm = __ballot(nz);
    int lane = t & 63;
    int w = t >> 6;
    if (t < 128 && lane == 0) cnts[w] = __popcll(bm);
    __syncthreads();
    if (nz) {
        int pos = __popcll(bm & ((1ull << lane) - 1)) + (w ? cnts[0] : 0);
        idxs[pos] = (unsigned short)t;   // d relative to d0
        cvals[pos] = c;
    }
    __syncthreads();
    int nnz = cnts[0] + cnts[1];

    int g  = t >> 7;      // wave-uniform: waves 0,1 -> 0; waves 2,3 -> 1
    int jj = t & 127;     // float4 column index (j = 4*jj)
    const float* Abase = A + ((size_t)i * 512 + d0) * 512 + (size_t)jj * 4;
    float4 acc = make_float4(0.f, 0.f, 0.f, 0.f);

    int k = g;
#pragma unroll 2
    for (; k + 6 < nnz; k += 8) {       // group g handles compacted rows k,k+2,k+4,k+6
        int dA = idxs[k], dB = idxs[k+2], dC = idxs[k+4], dD = idxs[k+6];
        float cA = cvals[k], cB = cvals[k+2], cC = cvals[k+4], cD = cvals[k+6];
        float4 a0 = *(const float4*)(Abase + ((size_t)dA << 9));
        float4 a1 = *(const float4*)(Abase + ((size_t)dB << 9));
        float4 a2 = *(const float4*)(Abase + ((size_t)dC << 9));
        float4 a3 = *(const float4*)(Abase + ((size_t)dD << 9));
        acc.x = fmaf(cA, a0.x, acc.x); acc.y = fmaf(cA, a0.y, acc.y);
        acc.z = fmaf(cA, a0.z, acc.z); acc.w = fmaf(cA, a0.w, acc.w);
        acc.x = fmaf(cB, a1.x, acc.x); acc.y = fmaf(cB, a1.y, acc.y);
        acc.z = fmaf(cB, a1.z, acc.z); acc.w = fmaf(cB, a1.w, acc.w);
        acc.x = fmaf(cC, a2.x, acc.x); acc.y = fmaf(cC, a2.y, acc.y);
        acc.z = fmaf(cC, a2.z, acc.z); acc.w = fmaf(cC, a2.w, acc.w);
        acc.x = fmaf(cD, a3.x, acc.x); acc.y = fmaf(cD, a3.y, acc.y);
        acc.z = fmaf(cD, a3.z, acc.z); acc.w = fmaf(cD, a3.w, acc.w);
    }
    for (; k < nnz; k += 2) {
        int dA = idxs[k]; float cA = cvals[k];
        float4 a0 = *(const float4*)(Abase + ((size_t)dA << 9));
        acc.x = fmaf(cA, a0.x, acc.x); acc.y = fmaf(cA, a0.y, acc.y);
        acc.z = fmaf(cA, a0.z, acc.z); acc.w = fmaf(cA, a0.w, acc.w);
    }

    if (g == 1) comb[jj] = acc;
    __syncthreads();
    if (g == 0) {
        float4 o = comb[jj];
        float* hp = ws + WS_HPRE + (size_t)(b & (NSLOT - 1)) * 512;
        int j = jj * 4;
        atomicAdd(&hp[j],     acc.x + o.x);
        atomicAdd(&hp[j + 1], acc.y + o.y);
        atomicAdd(&hp[j + 2], acc.z + o.z);
        atomicAdd(&hp[j + 3], acc.w + o.w);
    }
}

// ---------------------------------------------------------------------------
// Kernel 3: h = sigmoid(sum of slots); also writes out[1..512] = h.
// ---------------------------------------------------------------------------
__global__ __launch_bounds__(512) void k_h(float* __restrict__ ws, float* __restrict__ out)
{
    int t = threadIdx.x;
    float s = 0.f;
#pragma unroll
    for (int s2 = 0; s2 < NSLOT; ++s2) s += ws[WS_HPRE + s2 * 512 + t];
    float h = 1.f / (1.f + expf(-s));
    ws[WS_H + t] = h;
    out[1 + t] = h;
}

// ---------------------------------------------------------------------------
// Kernel 4: three matvecs against h: t1 = Wmu@h+bmu (rows 0..511),
// sp = Wsig@h+bsig (512..1023), al = Wal@h+bal (1024..1031). One wave/row.
// ---------------------------------------------------------------------------
__global__ __launch_bounds__(64) void k_mv3(const float* __restrict__ Wmu, const float* __restrict__ bmu,
    const float* __restrict__ Wsig, const float* __restrict__ bsig,
    const float* __restrict__ Wal, const float* __restrict__ bal,
    float* __restrict__ ws)
{
    int r = blockIdx.x;
    const float* Wrow; float bias; float* outp;
    if (r < 512)       { Wrow = Wmu  + (size_t)r * 512;          bias = bmu[r];          outp = ws + WS_T1 + r; }
    else if (r < 1024) { int rr = r - 512;  Wrow = Wsig + (size_t)rr * 512; bias = bsig[rr]; outp = ws + WS_SP + rr; }
    else               { int rr = r - 1024; Wrow = Wal  + (size_t)rr * 512; bias = bal[rr];  outp = ws + WS_AL + rr; }
    int l = threadIdx.x;
    const float4* W4 = (const float4*)Wrow;
    const float4* h4 = (const float4*)(ws + WS_H);
    float4 w0 = W4[2*l], w1 = W4[2*l+1];
    float4 h0 = h4[2*l], h1 = h4[2*l+1];
    float s = w0.x*h0.x + w0.y*h0.y + w0.z*h0.z + w0.w*h0.w
            + w1.x*h1.x + w1.y*h1.y + w1.z*h1.z + w1.w*h1.w;
#pragma unroll
    for (int off = 32; off > 0; off >>= 1) s += __shfl_down(s, off);
    if (l == 0) *outp = s + bias;
}

// ---------------------------------------------------------------------------
// Kernel 5: mu = Wmu2 @ t1 + bmu2. One wave per row.
// ---------------------------------------------------------------------------
__global__ __launch_bounds__(64) void k_mv1(const float* __restrict__ W, const float* __restrict__ bvec,
    float* __restrict__ ws)
{
    int r = blockIdx.x;
    int l = threadIdx.x;
    const float4* W4 = (const float4*)(W + (size_t)r * 512);
    const float4* x4 = (const float4*)(ws + WS_T1);
    float4 w0 = W4[2*l], w1 = W4[2*l+1];
    float4 x0 = x4[2*l], x1 = x4[2*l+1];
    float s = w0.x*x0.x + w0.y*x0.y + w0.z*x0.z + w0.w*x0.w
            + w1.x*x1.x + w1.y*x1.y + w1.z*x1.z + w1.w*x1.w;
#pragma unroll
    for (int off = 32; off > 0; off >>= 1) s += __shfl_down(s, off);
    if (l == 0) ws[WS_MU + r] = s + bvec[r];
}

// ---------------------------------------------------------------------------
// Kernel 6: mixture log-likelihood for the last row. Thread t = m*64 + x.
// log_comp[m] = -0.5*sum_x z^2 - sum_x sp - 32*log(2*pi), z=(nxt-mu)*exp(-sp)
// ll = lse(al + log_comp) - lse(al); out[0] = ll.
// ---------------------------------------------------------------------------
__global__ __launch_bounds__(512) void k_final(const float* __restrict__ X,
    float* __restrict__ ws, float* __restrict__ out)
{
    __shared__ float lc[8];
    int t = threadIdx.x;
    int m = t >> 6, x = t & 63;
    float nx = X[4095 * 64 + x];
    float mu = ws[WS_MU + t];
    float sp = ws[WS_SP + t];
    float z  = (nx - mu) * expf(-sp);
    float v  = 0.5f * z * z + sp;
#pragma unroll
    for (int off = 32; off > 0; off >>= 1) v += __shfl_down(v, off);
    if (x == 0) lc[m] = -v - 58.812066125099056f;   // 0.5*64*log(2*pi)
    __syncthreads();
    if (t == 0) {
        float al[8], g[8];
        float mx1 = -1e30f, mx2 = -1e30f;
#pragma unroll
        for (int q = 0; q < 8; ++q) {
            al[q] = ws[WS_AL + q];
            g[q]  = al[q] + lc[q];
            mx1 = fmaxf(mx1, al[q]);
            mx2 = fmaxf(mx2, g[q]);
        }
        float s1 = 0.f, s2 = 0.f;
#pragma unroll
        for (int q = 0; q < 8; ++q) { s1 += expf(al[q] - mx1); s2 += expf(g[q] - mx2); }
        out[0] = (mx2 + logf(s2)) - (mx1 + logf(s1));
    }
}

extern "C" void kernel_launch(void* const* d_in, const int* in_sizes, int n_in,
                              void* d_out, int out_size, void* d_ws, size_t ws_size,
                              hipStream_t stream)
{
    const float* X    = (const float*)d_in[0];
    const float* prev = (const float*)d_in[1];
    const float* A    = (const float*)d_in[2];
    const float* W1   = (const float*)d_in[3];
    const float* b1   = (const float*)d_in[4];
    const float* W2   = (const float*)d_in[5];
    const float* b2   = (const float*)d_in[6];
    const float* Wmu  = (const float*)d_in[7];
    const float* bmu  = (const float*)d_in[8];
    const float* Wmu2 = (const float*)d_in[9];
    const float* bmu2 = (const float*)d_in[10];
    const float* Wsig = (const float*)d_in[11];
    const float* bsig = (const float*)d_in[12];
    const float* Wal  = (const float*)d_in[13];
    const float* bal  = (const float*)d_in[14];
    float* out = (float*)d_out;
    float* ws  = (float*)d_ws;

    hipLaunchKernelGGL(k_e,        dim3(1),    dim3(512), 0, stream, X, W1, b1, W2, b2, ws);
    hipLaunchKernelGGL(k_contract, dim3(2048), dim3(256), 0, stream, A, prev, ws);
    hipLaunchKernelGGL(k_h,        dim3(1),    dim3(512), 0, stream, ws, out);
    hipLaunchKernelGGL(k_mv3,      dim3(1032), dim3(64),  0, stream, Wmu, bmu, Wsig, bsig, Wal, bal, ws);
    hipLaunchKernelGGL(k_mv1,      dim3(512),  dim3(64),  0, stream, Wmu2, bmu2, ws);
    hipLaunchKernelGGL(k_final,    dim3(1),    dim3(512), 0, stream, X, ws, out);
}

// Round 2
// 75.975 us; speedup vs baseline: 1.3818x; 1.3818x over previous
//
#include <hip/hip_runtime.h>
#include <math.h>

// ---- workspace layout (float offsets) ----
#define NSLOT    8
#define WS_E     0                        // 512: e (last row, layer 2 out)
#define WS_E1    512                      // 512: layer-1 activations
#define WS_HPRE  1024                     // NSLOT*512 partial accumulators
#define WS_H     (WS_HPRE + NSLOT*512)    // 512: h
#define WS_T1    (WS_H + 512)             // 512: h@Wmu.T + bmu
#define WS_SP    (WS_T1 + 512)            // 512: h@Wsig.T + bsig (= log sig)
#define WS_MU    (WS_SP + 512)            // 512: mu
#define WS_AL    (WS_MU + 512)            // 8:   h@Wal.T + bal

// ---------------------------------------------------------------------------
// k_e1: e1 = relu(W1 @ cur + b1), one wave per row (128 blocks x 4 waves).
// Also zeroes the NSLOT accumulator slots (must re-zero every launch).
// ---------------------------------------------------------------------------
__global__ __launch_bounds__(256) void k_e1(const float* __restrict__ X,
    const float* __restrict__ W1, const float* __restrict__ b1,
    float* __restrict__ ws)
{
    int t = threadIdx.x, b = blockIdx.x;
    int w = t >> 6, l = t & 63;
    int r = b * 4 + w;                       // 0..511
    float s = W1[(size_t)r * 64 + l] * X[4094 * 64 + l];
#pragma unroll
    for (int off = 32; off > 0; off >>= 1) s += __shfl_down(s, off);
    if (l == 0) ws[WS_E1 + r] = fmaxf(s + b1[r], 0.f);
    int gid = b * 256 + t;
    if (gid < NSLOT * 512) ws[WS_HPRE + gid] = 0.f;
}

// ---------------------------------------------------------------------------
// k_e2: e = relu(W2 @ e1 + b2), one wave per row (512 blocks).
// ---------------------------------------------------------------------------
__global__ __launch_bounds__(64) void k_e2(const float* __restrict__ W2,
    const float* __restrict__ b2, float* __restrict__ ws)
{
    int r = blockIdx.x, l = threadIdx.x;
    const float4* w4 = (const float4*)(W2 + (size_t)r * 512);
    const float4* x4 = (const float4*)(ws + WS_E1);
    float4 w0 = w4[2*l], w1 = w4[2*l+1];
    float4 x0 = x4[2*l], x1 = x4[2*l+1];
    float s = w0.x*x0.x + w0.y*x0.y + w0.z*x0.z + w0.w*x0.w
            + w1.x*x1.x + w1.y*x1.y + w1.z*x1.z + w1.w*x1.w;
#pragma unroll
    for (int off = 32; off > 0; off >>= 1) s += __shfl_down(s, off);
    if (l == 0) ws[WS_E + r] = fmaxf(s + b2[r], 0.f);
}

// ---------------------------------------------------------------------------
// k_contract: h_pre[j] += sum_{i,d} prev[i]*e[d]*A[i,d,j].
// Block b: i = b>>2, d-chunk = (b&3)*128. Ballot-compact nonzero e[d]
// (bit-exact skip), pad nnz to a multiple of 8 with zero-weight rows so the
// 4-deep float4 streaming loop runs tail-free.
// ---------------------------------------------------------------------------
__global__ __launch_bounds__(256) void k_contract(const float* __restrict__ A,
    const float* __restrict__ prev, float* __restrict__ ws)
{
    __shared__ float cvals[136];
    __shared__ unsigned short idxs[136];
    __shared__ int cnts[2];
    __shared__ float4 comb[128];

    int t = threadIdx.x;
    int b = blockIdx.x;
    int i = b >> 2;
    int d0 = (b & 3) << 7;
    const float* e = ws + WS_E;

    float c = 0.f; bool nz = false;
    if (t < 128) {
        c = prev[i] * e[d0 + t];
        nz = (c != 0.f);
    }
    unsigned long long bm = __ballot(nz);
    int lane = t & 63;
    int w = t >> 6;
    if (t < 128 && lane == 0) cnts[w] = __popcll(bm);
    __syncthreads();
    if (nz) {
        int pos = __popcll(bm & ((1ull << lane) - 1)) + (w ? cnts[0] : 0);
        idxs[pos] = (unsigned short)t;
        cvals[pos] = c;
    }
    int nnz = cnts[0] + cnts[1];
    int nnzp = (nnz + 7) & ~7;
    if (t < 8 && nnz + t < nnzp) {           // zero-weight padding rows
        cvals[nnz + t] = 0.f;
        idxs[nnz + t] = 0;
    }
    __syncthreads();

    int g  = t >> 7;      // wave-uniform: waves {0,1} -> 0; {2,3} -> 1
    int jj = t & 127;     // float4 column index
    const float* Abase = A + ((size_t)i * 512 + d0) * 512 + (size_t)jj * 4;
    float4 acc = make_float4(0.f, 0.f, 0.f, 0.f);

#pragma unroll 2
    for (int k = g; k + 6 < nnzp; k += 8) {  // group g: rows k,k+2,k+4,k+6
        int dA = idxs[k], dB = idxs[k+2], dC = idxs[k+4], dD = idxs[k+6];
        float cA = cvals[k], cB = cvals[k+2], cC = cvals[k+4], cD = cvals[k+6];
        float4 a0 = *(const float4*)(Abase + ((size_t)dA << 9));
        float4 a1 = *(const float4*)(Abase + ((size_t)dB << 9));
        float4 a2 = *(const float4*)(Abase + ((size_t)dC << 9));
        float4 a3 = *(const float4*)(Abase + ((size_t)dD << 9));
        acc.x = fmaf(cA, a0.x, acc.x); acc.y = fmaf(cA, a0.y, acc.y);
        acc.z = fmaf(cA, a0.z, acc.z); acc.w = fmaf(cA, a0.w, acc.w);
        acc.x = fmaf(cB, a1.x, acc.x); acc.y = fmaf(cB, a1.y, acc.y);
        acc.z = fmaf(cB, a1.z, acc.z); acc.w = fmaf(cB, a1.w, acc.w);
        acc.x = fmaf(cC, a2.x, acc.x); acc.y = fmaf(cC, a2.y, acc.y);
        acc.z = fmaf(cC, a2.z, acc.z); acc.w = fmaf(cC, a2.w, acc.w);
        acc.x = fmaf(cD, a3.x, acc.x); acc.y = fmaf(cD, a3.y, acc.y);
        acc.z = fmaf(cD, a3.z, acc.z); acc.w = fmaf(cD, a3.w, acc.w);
    }

    if (g == 1) comb[jj] = acc;
    __syncthreads();
    if (g == 0) {
        float4 o = comb[jj];
        float* hp = ws + WS_HPRE + (size_t)(b & (NSLOT - 1)) * 512;
        int j = jj * 4;
        atomicAdd(&hp[j],     acc.x + o.x);
        atomicAdd(&hp[j + 1], acc.y + o.y);
        atomicAdd(&hp[j + 2], acc.z + o.z);
        atomicAdd(&hp[j + 3], acc.w + o.w);
    }
}

// ---------------------------------------------------------------------------
// k_h: h = sigmoid(sum of slots); writes out[1..512] = h.
// ---------------------------------------------------------------------------
__global__ __launch_bounds__(512) void k_h(float* __restrict__ ws, float* __restrict__ out)
{
    int t = threadIdx.x;
    float s = 0.f;
#pragma unroll
    for (int s2 = 0; s2 < NSLOT; ++s2) s += ws[WS_HPRE + s2 * 512 + t];
    float h = 1.f / (1.f + expf(-s));
    ws[WS_H + t] = h;
    out[1 + t] = h;
}

// ---------------------------------------------------------------------------
// k_mv3: t1 = Wmu@h+bmu (rows 0..511), sp = Wsig@h+bsig (512..1023),
// al = Wal@h+bal (1024..1031). One wave per row.
// ---------------------------------------------------------------------------
__global__ __launch_bounds__(64) void k_mv3(const float* __restrict__ Wmu, const float* __restrict__ bmu,
    const float* __restrict__ Wsig, const float* __restrict__ bsig,
    const float* __restrict__ Wal, const float* __restrict__ bal,
    float* __restrict__ ws)
{
    int r = blockIdx.x;
    const float* Wrow; float bias; float* outp;
    if (r < 512)       { Wrow = Wmu  + (size_t)r * 512;          bias = bmu[r];          outp = ws + WS_T1 + r; }
    else if (r < 1024) { int rr = r - 512;  Wrow = Wsig + (size_t)rr * 512; bias = bsig[rr]; outp = ws + WS_SP + rr; }
    else               { int rr = r - 1024; Wrow = Wal  + (size_t)rr * 512; bias = bal[rr];  outp = ws + WS_AL + rr; }
    int l = threadIdx.x;
    const float4* W4 = (const float4*)Wrow;
    const float4* h4 = (const float4*)(ws + WS_H);
    float4 w0 = W4[2*l], w1 = W4[2*l+1];
    float4 h0 = h4[2*l], h1 = h4[2*l+1];
    float s = w0.x*h0.x + w0.y*h0.y + w0.z*h0.z + w0.w*h0.w
            + w1.x*h1.x + w1.y*h1.y + w1.z*h1.z + w1.w*h1.w;
#pragma unroll
    for (int off = 32; off > 0; off >>= 1) s += __shfl_down(s, off);
    if (l == 0) *outp = s + bias;
}

// ---------------------------------------------------------------------------
// k_mv1: mu = Wmu2 @ t1 + bmu2. One wave per row.
// ---------------------------------------------------------------------------
__global__ __launch_bounds__(64) void k_mv1(const float* __restrict__ W, const float* __restrict__ bvec,
    float* __restrict__ ws)
{
    int r = blockIdx.x;
    int l = threadIdx.x;
    const float4* W4 = (const float4*)(W + (size_t)r * 512);
    const float4* x4 = (const float4*)(ws + WS_T1);
    float4 w0 = W4[2*l], w1 = W4[2*l+1];
    float4 x0 = x4[2*l], x1 = x4[2*l+1];
    float s = w0.x*x0.x + w0.y*x0.y + w0.z*x0.z + w0.w*x0.w
            + w1.x*x1.x + w1.y*x1.y + w1.z*x1.z + w1.w*x1.w;
#pragma unroll
    for (int off = 32; off > 0; off >>= 1) s += __shfl_down(s, off);
    if (l == 0) ws[WS_MU + r] = s + bvec[r];
}

// ---------------------------------------------------------------------------
// k_final: mixture log-likelihood, thread t = m*64 + x.
// ---------------------------------------------------------------------------
__global__ __launch_bounds__(512) void k_final(const float* __restrict__ X,
    float* __restrict__ ws, float* __restrict__ out)
{
    __shared__ float lc[8];
    int t = threadIdx.x;
    int m = t >> 6, x = t & 63;
    float nx = X[4095 * 64 + x];
    float mu = ws[WS_MU + t];
    float sp = ws[WS_SP + t];
    float z  = (nx - mu) * expf(-sp);
    float v  = 0.5f * z * z + sp;
#pragma unroll
    for (int off = 32; off > 0; off >>= 1) v += __shfl_down(v, off);
    if (x == 0) lc[m] = -v - 58.812066125099056f;   // 0.5*64*log(2*pi)
    __syncthreads();
    if (t == 0) {
        float al[8], g[8];
        float mx1 = -1e30f, mx2 = -1e30f;
#pragma unroll
        for (int q = 0; q < 8; ++q) {
            al[q] = ws[WS_AL + q];
            g[q]  = al[q] + lc[q];
            mx1 = fmaxf(mx1, al[q]);
            mx2 = fmaxf(mx2, g[q]);
        }
        float s1 = 0.f, s2 = 0.f;
#pragma unroll
        for (int q = 0; q < 8; ++q) { s1 += expf(al[q] - mx1); s2 += expf(g[q] - mx2); }
        out[0] = (mx2 + logf(s2)) - (mx1 + logf(s1));
    }
}

extern "C" void kernel_launch(void* const* d_in, const int* in_sizes, int n_in,
                              void* d_out, int out_size, void* d_ws, size_t ws_size,
                              hipStream_t stream)
{
    const float* X    = (const float*)d_in[0];
    const float* prev = (const float*)d_in[1];
    const float* A    = (const float*)d_in[2];
    const float* W1   = (const float*)d_in[3];
    const float* b1   = (const float*)d_in[4];
    const float* W2   = (const float*)d_in[5];
    const float* b2   = (const float*)d_in[6];
    const float* Wmu  = (const float*)d_in[7];
    const float* bmu  = (const float*)d_in[8];
    const float* Wmu2 = (const float*)d_in[9];
    const float* bmu2 = (const float*)d_in[10];
    const float* Wsig = (const float*)d_in[11];
    const float* bsig = (const float*)d_in[12];
    const float* Wal  = (const float*)d_in[13];
    const float* bal  = (const float*)d_in[14];
    float* out = (float*)d_out;
    float* ws  = (float*)d_ws;

    hipLaunchKernelGGL(k_e1,       dim3(128),  dim3(256), 0, stream, X, W1, b1, ws);
    hipLaunchKernelGGL(k_e2,       dim3(512),  dim3(64),  0, stream, W2, b2, ws);
    hipLaunchKernelGGL(k_contract, dim3(2048), dim3(256), 0, stream, A, prev, ws);
    hipLaunchKernelGGL(k_h,        dim3(1),    dim3(512), 0, stream, ws, out);
    hipLaunchKernelGGL(k_mv3,      dim3(1032), dim3(64),  0, stream, Wmu, bmu, Wsig, bsig, Wal, bal, ws);
    hipLaunchKernelGGL(k_mv1,      dim3(512),  dim3(64),  0, stream, Wmu2, bmu2, ws);
    hipLaunchKernelGGL(k_final,    dim3(1),    dim3(512), 0, stream, X, ws, out);
}